// Round 4
// baseline (400.566 us; speedup 1.0000x reference)
//
#include <hip/hip_runtime.h>
#include <hip/hip_bf16.h>

#define N_NODES 50000
#define N_EDGES 800000
#define M_IN 512
#define H_OUT 512

typedef __attribute__((ext_vector_type(8))) short    bf16x8;  // MFMA A/B frag (4 VGPR)
typedef __attribute__((ext_vector_type(4))) float    f32x4;   // MFMA C/D frag
typedef __attribute__((ext_vector_type(8))) unsigned short u16x8;

__device__ inline float bf2f(unsigned short u) {
    unsigned int x = ((unsigned int)u) << 16;
    return __builtin_bit_cast(float, x);
}
__device__ inline unsigned short f2bf(float f) {   // round-to-nearest-even
    unsigned int x = __builtin_bit_cast(unsigned int, f);
    return (unsigned short)((x + 0x7FFF + ((x >> 16) & 1)) >> 16);
}
__device__ inline void gload_lds16(const void* g, void* lds) {
    __builtin_amdgcn_global_load_lds(
        (const __attribute__((address_space(1))) void*)g,
        (__attribute__((address_space(3))) void*)lds, 16, 0, 0);
}

// ---------------------------------------------------------------------------
// prep: fused convx (blocks [0,12500)) + convw (12500..13524) + hist (rest).
// All three are independent; fusing saves launches and fills the GPU.
// ---------------------------------------------------------------------------
#define CONVX_B 12500
#define CONVW_B 1024
#define HIST_B  3125

__global__ __launch_bounds__(256) void prep_kernel(
    const float* __restrict__ X, unsigned short* __restrict__ Xb,
    const float* __restrict__ W, unsigned short* __restrict__ Wt,
    const int* __restrict__ edst, int* __restrict__ counts)
{
    const int b = blockIdx.x;
    if (b < CONVX_B) {
        const size_t i = (size_t)b * 256 + threadIdx.x;        // 3.2M threads x 8 f32
        const float4 a = ((const float4*)X)[2 * i];
        const float4 c = ((const float4*)X)[2 * i + 1];
        u16x8 o;
        o[0] = f2bf(a.x); o[1] = f2bf(a.y); o[2] = f2bf(a.z); o[3] = f2bf(a.w);
        o[4] = f2bf(c.x); o[5] = f2bf(c.y); o[6] = f2bf(c.z); o[7] = f2bf(c.w);
        *(u16x8*)(Xb + i * 8) = o;
    } else if (b < CONVX_B + CONVW_B) {
        const int id = (b - CONVX_B) * 256 + threadIdx.x;      // 262144 = 512*512
        const int n = id >> 9, k = id & 511;
        Wt[(size_t)n * 512 + k] = f2bf(W[(size_t)k * 512 + n]);
    } else {
        const int e = (b - CONVX_B - CONVW_B) * 256 + threadIdx.x;  // 800000 exact
        atomicAdd(&counts[edst[e]], 1);
    }
}

// ---------------------------------------------------------------------------
// scan: 1024-thread single-block exclusive scan of 50000 counts -> offs[0..N];
// also zeroes the counts array (reused as build cursor) — saves a memset.
// ---------------------------------------------------------------------------
__global__ __launch_bounds__(1024) void scan_kernel(
    int* __restrict__ counts, int* __restrict__ offs)
{
    __shared__ int wsum[16];
    const int tid  = threadIdx.x;
    const int lane = tid & 63;
    const int wv   = tid >> 6;
    const int CH   = (N_NODES + 1023) / 1024;   // 49
    const int b    = tid * CH;
    const int e    = min(b + CH, N_NODES);

    int s = 0;
    for (int i = b; i < e; ++i) s += counts[i];

    int x = s;                                   // inclusive scan within wave
#pragma unroll
    for (int d = 1; d < 64; d <<= 1) {
        int y = __shfl_up(x, d, 64);
        if (lane >= d) x += y;
    }
    if (lane == 63) wsum[wv] = x;
    __syncthreads();
    if (tid == 0) {
        int run = 0;
#pragma unroll
        for (int i = 0; i < 16; ++i) { int t = wsum[i]; wsum[i] = run; run += t; }
    }
    __syncthreads();

    int run = wsum[wv] + (x - s);                // exclusive prefix for this thread
    for (int i = b; i < e; ++i) {
        int c = counts[i];
        offs[i]   = run;
        counts[i] = 0;                           // becomes the build cursor
        run += c;
    }
    if (e == N_NODES) offs[N_NODES] = run;
}

__global__ __launch_bounds__(256) void build_kernel(
    const int* __restrict__ esrc, const int* __restrict__ edst,
    const float* __restrict__ eval,
    const int* __restrict__ offs, int* __restrict__ cursor,
    int* __restrict__ srcs, float* __restrict__ vals)
{
    const int e = blockIdx.x * 256 + threadIdx.x;
    if (e >= N_EDGES) return;
    const int d   = edst[e];
    const int pos = offs[d] + atomicAdd(&cursor[d], 1);
    srcs[pos] = esrc[e];
    vals[pos] = eval[e];
}

// ---------------------------------------------------------------------------
// Gather (bf16 in / fp32 accum / bf16 out): one wave per dst node.
// Unroll 4: four independent row loads in flight per lane for latency hiding.
// ---------------------------------------------------------------------------
__global__ __launch_bounds__(256) void gather_kernel(
    const unsigned short* __restrict__ Xb,
    const int*   __restrict__ offs,
    const int*   __restrict__ srcs,
    const float* __restrict__ vals,
    unsigned short* __restrict__ Yb)
{
    const int node = blockIdx.x * 4 + (threadIdx.x >> 6);
    const int lane = threadIdx.x & 63;
    if (node >= N_NODES) return;

    const int beg = offs[node];
    const int end = offs[node + 1];

    float acc[8] = {};

    int e = beg;
    for (; e + 3 < end; e += 4) {
        const int   s0 = srcs[e],     s1 = srcs[e + 1];
        const int   s2 = srcs[e + 2], s3 = srcs[e + 3];
        const float v0 = vals[e],     v1 = vals[e + 1];
        const float v2 = vals[e + 2], v3 = vals[e + 3];
        const u16x8 p0 = *(const u16x8*)(Xb + (size_t)s0 * M_IN + lane * 8);
        const u16x8 p1 = *(const u16x8*)(Xb + (size_t)s1 * M_IN + lane * 8);
        const u16x8 p2 = *(const u16x8*)(Xb + (size_t)s2 * M_IN + lane * 8);
        const u16x8 p3 = *(const u16x8*)(Xb + (size_t)s3 * M_IN + lane * 8);
#pragma unroll
        for (int j = 0; j < 8; ++j) {
            acc[j] += bf2f(p0[j]) * v0 + bf2f(p1[j]) * v1;
            acc[j] += bf2f(p2[j]) * v2 + bf2f(p3[j]) * v3;
        }
    }
    for (; e < end; ++e) {
        const int   s0 = srcs[e];
        const float v0 = vals[e];
        const u16x8 p0 = *(const u16x8*)(Xb + (size_t)s0 * M_IN + lane * 8);
#pragma unroll
        for (int j = 0; j < 8; ++j) acc[j] += bf2f(p0[j]) * v0;
    }

    u16x8 o;
#pragma unroll
    for (int j = 0; j < 8; ++j) o[j] = f2bf(acc[j]);
    *(u16x8*)(Yb + (size_t)node * M_IN + lane * 8) = o;
}

// ---------------------------------------------------------------------------
// out = relu(Yb @ Wt^T) — bf16 MFMA 16x16x32, fp32 accum.
// 128x128 tile, BK=32, 4 waves (2x2). Minimum 2-phase pipeline (catalog T3-min):
// double-buffered LDS; STAGE(next) issued before ds_read+MFMA of current;
// vmcnt(0) AFTER the MFMAs (latency hidden) + raw s_barrier, once per K-tile.
// Same 16B-chunk XOR swizzle as round 3 (pre-swizzled global src, swizzled read).
// ---------------------------------------------------------------------------
#define BM 128
#define BN 128
#define BK 32
#define NT (M_IN / BK)   // 16

__global__ __launch_bounds__(256, 2) void gemm_mfma_kernel(
    const unsigned short* __restrict__ Yb,
    const unsigned short* __restrict__ Wt,
    float* __restrict__ out)
{
    __shared__ unsigned short As[2][BM * BK];  // 2 x 8 KB
    __shared__ unsigned short Bs[2][BN * BK];  // 2 x 8 KB

    const int tid  = threadIdx.x;
    const int lane = tid & 63;
    const int wid  = tid >> 6;
    const int wr   = wid >> 1;
    const int wc   = wid & 1;
    // blockIdx.x = col tile (innermost, 4 tiles share A panel via L2)
    const int row0 = blockIdx.y * BM;
    const int col0 = blockIdx.x * BN;

    f32x4 acc[4][4] = {};

    // staging geometry: 2 x 16B chunks per thread per matrix
    int srow[2], ksw[2], ldsb[2];
#pragma unroll
    for (int i = 0; i < 2; ++i) {
        const int b   = (i * 256 + tid) * 16;
        const int row = b >> 6;                    // 64 B per tile row
        const int cir = (b >> 4) & 3;
        srow[i] = row;
        ksw[i]  = (cir ^ ((row >> 1) & 3)) << 3;   // swizzled k element offset
        ldsb[i] = b;
    }
    int agr[2];
#pragma unroll
    for (int i = 0; i < 2; ++i) {
        int gr = row0 + srow[i];
        if (gr >= N_NODES) gr = N_NODES - 1;       // clamp; epilogue guards stores
        agr[i] = gr;
    }

    // ds_read byte addresses (logical chunk c = lane>>4, swizzled)
    int abyte[4], bbyte[4];
    const int c = lane >> 4;
#pragma unroll
    for (int m = 0; m < 4; ++m) {
        const int ra = wr * 64 + m * 16 + (lane & 15);
        abyte[m] = ra * 64 + ((c ^ ((ra >> 1) & 3)) << 4);
        const int rb = wc * 64 + m * 16 + (lane & 15);
        bbyte[m] = rb * 64 + ((c ^ ((rb >> 1) & 3)) << 4);
    }

#define STAGE(buf, k0)                                                          \
    do {                                                                        \
        _Pragma("unroll")                                                       \
        for (int i = 0; i < 2; ++i) {                                           \
            gload_lds16(Yb + (size_t)agr[i] * M_IN + (k0) + ksw[i],             \
                        (char*)As[buf] + ldsb[i]);                              \
            gload_lds16(Wt + (size_t)(col0 + srow[i]) * M_IN + (k0) + ksw[i],   \
                        (char*)Bs[buf] + ldsb[i]);                              \
        }                                                                       \
    } while (0)

    // prologue
    STAGE(0, 0);
    asm volatile("s_waitcnt vmcnt(0)" ::: "memory");
    __builtin_amdgcn_s_barrier();

    int cur = 0;
    for (int t = 0; t < NT; ++t) {
        if (t + 1 < NT) STAGE(cur ^ 1, (t + 1) * BK);

        bf16x8 af[4], bfr[4];
#pragma unroll
        for (int m = 0; m < 4; ++m)
            af[m]  = *(const bf16x8*)((const char*)As[cur] + abyte[m]);
#pragma unroll
        for (int n = 0; n < 4; ++n)
            bfr[n] = *(const bf16x8*)((const char*)Bs[cur] + bbyte[n]);

#pragma unroll
        for (int m = 0; m < 4; ++m)
#pragma unroll
            for (int n = 0; n < 4; ++n)
                acc[m][n] = __builtin_amdgcn_mfma_f32_16x16x32_bf16(
                    af[m], bfr[n], acc[m][n], 0, 0, 0);

        if (t + 1 < NT) {
            asm volatile("s_waitcnt vmcnt(0)" ::: "memory");  // next tile staged
            __builtin_amdgcn_s_barrier();                      // all reads of cur done
        }
        cur ^= 1;
    }
#undef STAGE

    // epilogue: C/D map col=lane&15, row=(lane>>4)*4+r  [measured m89]
#pragma unroll
    for (int m = 0; m < 4; ++m) {
#pragma unroll
        for (int n = 0; n < 4; ++n) {
#pragma unroll
            for (int r = 0; r < 4; ++r) {
                const int row = row0 + wr * 64 + m * 16 + (lane >> 4) * 4 + r;
                const int col = col0 + wc * 64 + n * 16 + (lane & 15);
                if (row < N_NODES)
                    out[(size_t)row * H_OUT + col] = fmaxf(acc[m][n][r], 0.f);
            }
        }
    }
}

extern "C" void kernel_launch(void* const* d_in, const int* in_sizes, int n_in,
                              void* d_out, int out_size, void* d_ws, size_t ws_size,
                              hipStream_t stream) {
    const float* X    = (const float*)d_in[0];
    const float* W    = (const float*)d_in[1];
    const int*   esrc = (const int*)d_in[2];
    const int*   edst = (const int*)d_in[3];
    const float* eval = (const float*)d_in[4];
    float* out = (float*)d_out;

    // workspace layout (16B-aligned)
    char* w = (char*)d_ws;
    unsigned short* Yb = (unsigned short*)w;  w += (size_t)N_NODES * M_IN * 2;  // 51.2 MB
    unsigned short* Xb = (unsigned short*)w;  w += (size_t)N_NODES * M_IN * 2;  // 51.2 MB
    unsigned short* Wt = (unsigned short*)w;  w += (size_t)M_IN * H_OUT * 2;    // 0.5 MB
    int*   offs   = (int*)w;                  w += (size_t)(N_NODES + 1) * 4;
    int*   cursor = (int*)w;                  w += (size_t)N_NODES * 4;         // counts/cursor
    int*   srcs   = (int*)w;                  w += (size_t)N_EDGES * 4;
    float* vals   = (float*)w;

    hipMemsetAsync(cursor, 0, N_NODES * sizeof(int), stream);

    prep_kernel<<<CONVX_B + CONVW_B + HIST_B, 256, 0, stream>>>(
        X, Xb, W, Wt, edst, cursor);

    scan_kernel<<<1, 1024, 0, stream>>>(cursor, offs);   // also zeroes cursor

    build_kernel<<<(N_EDGES + 255) / 256, 256, 0, stream>>>(
        esrc, edst, eval, offs, cursor, srcs, vals);

    gather_kernel<<<(N_NODES + 3) / 4, 256, 0, stream>>>(Xb, offs, srcs, vals, Yb);

    dim3 grid(H_OUT / BN, (N_NODES + BM - 1) / BM);      // (4, 391), col-tiles innermost
    gemm_mfma_kernel<<<grid, 256, 0, stream>>>(Yb, Wt, out);
}

// Round 5
// 380.857 us; speedup vs baseline: 1.0517x; 1.0517x over previous
//
#include <hip/hip_runtime.h>
#include <hip/hip_bf16.h>

#define N_NODES 50000
#define N_EDGES 800000
#define M_IN 512
#define H_OUT 512

typedef __attribute__((ext_vector_type(8))) short    bf16x8;  // MFMA A/B frag (4 VGPR)
typedef __attribute__((ext_vector_type(4))) float    f32x4;   // MFMA C/D frag
typedef __attribute__((ext_vector_type(8))) unsigned short u16x8;
typedef __attribute__((ext_vector_type(4))) unsigned short u16x4;

__device__ inline float bf2f(unsigned short u) {
    unsigned int x = ((unsigned int)u) << 16;
    return __builtin_bit_cast(float, x);
}
__device__ inline unsigned short f2bf(float f) {   // round-to-nearest-even
    unsigned int x = __builtin_bit_cast(unsigned int, f);
    return (unsigned short)((x + 0x7FFF + ((x >> 16) & 1)) >> 16);
}
__device__ inline void gload_lds16(const void* g, void* lds) {
    __builtin_amdgcn_global_load_lds(
        (const __attribute__((address_space(1))) void*)g,
        (__attribute__((address_space(3))) void*)lds, 16, 0, 0);
}

// ---------------------------------------------------------------------------
// prep: fused convx (blocks [0,12500)) + convw + hist. All independent.
// ---------------------------------------------------------------------------
#define CONVX_B 12500
#define CONVW_B 1024
#define HIST_B  3125

__global__ __launch_bounds__(256) void prep_kernel(
    const float* __restrict__ X, unsigned short* __restrict__ Xb,
    const float* __restrict__ W, unsigned short* __restrict__ Wt,
    const int* __restrict__ edst, int* __restrict__ counts)
{
    const int b = blockIdx.x;
    if (b < CONVX_B) {
        const size_t i = (size_t)b * 256 + threadIdx.x;        // 3.2M threads x 8 f32
        const float4 a = ((const float4*)X)[2 * i];
        const float4 c = ((const float4*)X)[2 * i + 1];
        u16x8 o;
        o[0] = f2bf(a.x); o[1] = f2bf(a.y); o[2] = f2bf(a.z); o[3] = f2bf(a.w);
        o[4] = f2bf(c.x); o[5] = f2bf(c.y); o[6] = f2bf(c.z); o[7] = f2bf(c.w);
        *(u16x8*)(Xb + i * 8) = o;
    } else if (b < CONVX_B + CONVW_B) {
        const int id = (b - CONVX_B) * 256 + threadIdx.x;      // 262144 = 512*512
        const int n = id >> 9, k = id & 511;
        Wt[(size_t)n * 512 + k] = f2bf(W[(size_t)k * 512 + n]);
    } else {
        const int e = (b - CONVX_B - CONVW_B) * 256 + threadIdx.x;  // 800000 exact
        atomicAdd(&counts[edst[e]], 1);
    }
}

// ---------------------------------------------------------------------------
// scan: 1024-thread single-block exclusive scan of counts -> offs[0..N];
// also zeroes counts (reused as build cursor).
// ---------------------------------------------------------------------------
__global__ __launch_bounds__(1024) void scan_kernel(
    int* __restrict__ counts, int* __restrict__ offs)
{
    __shared__ int wsum[16];
    const int tid  = threadIdx.x;
    const int lane = tid & 63;
    const int wv   = tid >> 6;
    const int CH   = (N_NODES + 1023) / 1024;   // 49
    const int b    = tid * CH;
    const int e    = min(b + CH, N_NODES);

    int s = 0;
    for (int i = b; i < e; ++i) s += counts[i];

    int x = s;
#pragma unroll
    for (int d = 1; d < 64; d <<= 1) {
        int y = __shfl_up(x, d, 64);
        if (lane >= d) x += y;
    }
    if (lane == 63) wsum[wv] = x;
    __syncthreads();
    if (tid == 0) {
        int run = 0;
#pragma unroll
        for (int i = 0; i < 16; ++i) { int t = wsum[i]; wsum[i] = run; run += t; }
    }
    __syncthreads();

    int run = wsum[wv] + (x - s);
    for (int i = b; i < e; ++i) {
        int c = counts[i];
        offs[i]   = run;
        counts[i] = 0;
        run += c;
    }
    if (e == N_NODES) offs[N_NODES] = run;
}

// build: packed (src, val-bits) 8B store — one random line per edge, not two.
__global__ __launch_bounds__(256) void build_kernel(
    const int* __restrict__ esrc, const int* __restrict__ edst,
    const float* __restrict__ eval,
    const int* __restrict__ offs, int* __restrict__ cursor,
    int2* __restrict__ pairs)
{
    const int e = blockIdx.x * 256 + threadIdx.x;
    if (e >= N_EDGES) return;
    const int d   = edst[e];
    const int pos = offs[d] + atomicAdd(&cursor[d], 1);
    int2 p;
    p.x = esrc[e];
    p.y = __float_as_int(eval[e]);
    pairs[pos] = p;
}

// ---------------------------------------------------------------------------
// Gather: TWO waves per dst node (256 cols each, dwordx2/lane/edge).
// 2x wave count vs round 4 -> better latency hiding + half-length stragglers.
// ---------------------------------------------------------------------------
__global__ __launch_bounds__(256) void gather_kernel(
    const unsigned short* __restrict__ Xb,
    const int*  __restrict__ offs,
    const int2* __restrict__ pairs,
    unsigned short* __restrict__ Yb)
{
    const int gw   = blockIdx.x * 4 + (threadIdx.x >> 6);  // global wave id
    const int node = gw >> 1;
    const int half = gw & 1;
    const int lane = threadIdx.x & 63;
    if (node >= N_NODES) return;

    const int beg = offs[node];
    const int end = offs[node + 1];
    const int col = half * 256 + lane * 4;                 // first of 4 columns

    float a0 = 0.f, a1 = 0.f, a2 = 0.f, a3 = 0.f;

    int e = beg;
    for (; e + 3 < end; e += 4) {
        const int2 q0 = pairs[e],     q1 = pairs[e + 1];
        const int2 q2 = pairs[e + 2], q3 = pairs[e + 3];
        const u16x4 x0 = *(const u16x4*)(Xb + (size_t)q0.x * M_IN + col);
        const u16x4 x1 = *(const u16x4*)(Xb + (size_t)q1.x * M_IN + col);
        const u16x4 x2 = *(const u16x4*)(Xb + (size_t)q2.x * M_IN + col);
        const u16x4 x3 = *(const u16x4*)(Xb + (size_t)q3.x * M_IN + col);
        const float v0 = __int_as_float(q0.y), v1 = __int_as_float(q1.y);
        const float v2 = __int_as_float(q2.y), v3 = __int_as_float(q3.y);
        a0 += bf2f(x0[0]) * v0 + bf2f(x1[0]) * v1 + bf2f(x2[0]) * v2 + bf2f(x3[0]) * v3;
        a1 += bf2f(x0[1]) * v0 + bf2f(x1[1]) * v1 + bf2f(x2[1]) * v2 + bf2f(x3[1]) * v3;
        a2 += bf2f(x0[2]) * v0 + bf2f(x1[2]) * v1 + bf2f(x2[2]) * v2 + bf2f(x3[2]) * v3;
        a3 += bf2f(x0[3]) * v0 + bf2f(x1[3]) * v1 + bf2f(x2[3]) * v2 + bf2f(x3[3]) * v3;
    }
    for (; e < end; ++e) {
        const int2  q0 = pairs[e];
        const u16x4 x0 = *(const u16x4*)(Xb + (size_t)q0.x * M_IN + col);
        const float v0 = __int_as_float(q0.y);
        a0 += bf2f(x0[0]) * v0;
        a1 += bf2f(x0[1]) * v0;
        a2 += bf2f(x0[2]) * v0;
        a3 += bf2f(x0[3]) * v0;
    }

    u16x4 o;
    o[0] = f2bf(a0); o[1] = f2bf(a1); o[2] = f2bf(a2); o[3] = f2bf(a3);
    *(u16x4*)(Yb + (size_t)node * M_IN + col) = o;
}

// ---------------------------------------------------------------------------
// out = relu(Yb @ Wt^T) — bf16 MFMA 16x16x32, fp32 accum. (unchanged round 4)
// 128x128 tile, BK=32, 4 waves, 2-phase double-buffered pipeline.
// ---------------------------------------------------------------------------
#define BM 128
#define BN 128
#define BK 32
#define NT (M_IN / BK)   // 16

__global__ __launch_bounds__(256, 2) void gemm_mfma_kernel(
    const unsigned short* __restrict__ Yb,
    const unsigned short* __restrict__ Wt,
    float* __restrict__ out)
{
    __shared__ unsigned short As[2][BM * BK];  // 2 x 8 KB
    __shared__ unsigned short Bs[2][BN * BK];  // 2 x 8 KB

    const int tid  = threadIdx.x;
    const int lane = tid & 63;
    const int wid  = tid >> 6;
    const int wr   = wid >> 1;
    const int wc   = wid & 1;
    const int row0 = blockIdx.y * BM;
    const int col0 = blockIdx.x * BN;

    f32x4 acc[4][4] = {};

    int srow[2], ksw[2], ldsb[2];
#pragma unroll
    for (int i = 0; i < 2; ++i) {
        const int b   = (i * 256 + tid) * 16;
        const int row = b >> 6;
        const int cir = (b >> 4) & 3;
        srow[i] = row;
        ksw[i]  = (cir ^ ((row >> 1) & 3)) << 3;
        ldsb[i] = b;
    }
    int agr[2];
#pragma unroll
    for (int i = 0; i < 2; ++i) {
        int gr = row0 + srow[i];
        if (gr >= N_NODES) gr = N_NODES - 1;
        agr[i] = gr;
    }

    int abyte[4], bbyte[4];
    const int c = lane >> 4;
#pragma unroll
    for (int m = 0; m < 4; ++m) {
        const int ra = wr * 64 + m * 16 + (lane & 15);
        abyte[m] = ra * 64 + ((c ^ ((ra >> 1) & 3)) << 4);
        const int rb = wc * 64 + m * 16 + (lane & 15);
        bbyte[m] = rb * 64 + ((c ^ ((rb >> 1) & 3)) << 4);
    }

#define STAGE(buf, k0)                                                          \
    do {                                                                        \
        _Pragma("unroll")                                                       \
        for (int i = 0; i < 2; ++i) {                                           \
            gload_lds16(Yb + (size_t)agr[i] * M_IN + (k0) + ksw[i],             \
                        (char*)As[buf] + ldsb[i]);                              \
            gload_lds16(Wt + (size_t)(col0 + srow[i]) * M_IN + (k0) + ksw[i],   \
                        (char*)Bs[buf] + ldsb[i]);                              \
        }                                                                       \
    } while (0)

    STAGE(0, 0);
    asm volatile("s_waitcnt vmcnt(0)" ::: "memory");
    __builtin_amdgcn_s_barrier();

    int cur = 0;
    for (int t = 0; t < NT; ++t) {
        if (t + 1 < NT) STAGE(cur ^ 1, (t + 1) * BK);

        bf16x8 af[4], bfr[4];
#pragma unroll
        for (int m = 0; m < 4; ++m)
            af[m]  = *(const bf16x8*)((const char*)As[cur] + abyte[m]);
#pragma unroll
        for (int n = 0; n < 4; ++n)
            bfr[n] = *(const bf16x8*)((const char*)Bs[cur] + bbyte[n]);

#pragma unroll
        for (int m = 0; m < 4; ++m)
#pragma unroll
            for (int n = 0; n < 4; ++n)
                acc[m][n] = __builtin_amdgcn_mfma_f32_16x16x32_bf16(
                    af[m], bfr[n], acc[m][n], 0, 0, 0);

        if (t + 1 < NT) {
            asm volatile("s_waitcnt vmcnt(0)" ::: "memory");
            __builtin_amdgcn_s_barrier();
        }
        cur ^= 1;
    }
#undef STAGE

    // epilogue: C/D map col=lane&15, row=(lane>>4)*4+r  [measured m89]
#pragma unroll
    for (int m = 0; m < 4; ++m) {
#pragma unroll
        for (int n = 0; n < 4; ++n) {
#pragma unroll
            for (int r = 0; r < 4; ++r) {
                const int row = row0 + wr * 64 + m * 16 + (lane >> 4) * 4 + r;
                const int col = col0 + wc * 64 + n * 16 + (lane & 15);
                if (row < N_NODES)
                    out[(size_t)row * H_OUT + col] = fmaxf(acc[m][n][r], 0.f);
            }
        }
    }
}

extern "C" void kernel_launch(void* const* d_in, const int* in_sizes, int n_in,
                              void* d_out, int out_size, void* d_ws, size_t ws_size,
                              hipStream_t stream) {
    const float* X    = (const float*)d_in[0];
    const float* W    = (const float*)d_in[1];
    const int*   esrc = (const int*)d_in[2];
    const int*   edst = (const int*)d_in[3];
    const float* eval = (const float*)d_in[4];
    float* out = (float*)d_out;

    // workspace layout (16B-aligned)
    char* w = (char*)d_ws;
    unsigned short* Yb = (unsigned short*)w;  w += (size_t)N_NODES * M_IN * 2;  // 51.2 MB
    unsigned short* Xb = (unsigned short*)w;  w += (size_t)N_NODES * M_IN * 2;  // 51.2 MB
    unsigned short* Wt = (unsigned short*)w;  w += (size_t)M_IN * H_OUT * 2;    // 0.5 MB
    int*   offs   = (int*)w;                  w += (size_t)(N_NODES + 4) * 4;   // keep 16B align
    int*   cursor = (int*)w;                  w += (size_t)N_NODES * 4;
    int2*  pairs  = (int2*)w;                                                   // 6.4 MB

    hipMemsetAsync(cursor, 0, N_NODES * sizeof(int), stream);

    prep_kernel<<<CONVX_B + CONVW_B + HIST_B, 256, 0, stream>>>(
        X, Xb, W, Wt, edst, cursor);

    scan_kernel<<<1, 1024, 0, stream>>>(cursor, offs);   // also zeroes cursor

    build_kernel<<<(N_EDGES + 255) / 256, 256, 0, stream>>>(
        esrc, edst, eval, offs, cursor, pairs);

    // 2 waves per node -> 100000 waves -> 25000 blocks of 4 waves
    gather_kernel<<<(2 * N_NODES + 3) / 4, 256, 0, stream>>>(Xb, offs, pairs, Yb);

    dim3 grid(H_OUT / BN, (N_NODES + BM - 1) / BM);      // (4, 391), col-tiles innermost
    gemm_mfma_kernel<<<grid, 256, 0, stream>>>(Yb, Wt, out);
}